// Round 2
// baseline (302.920 us; speedup 1.0000x reference)
//
#include <hip/hip_runtime.h>

// Problem constants (match reference)
#define NB 8
#define HH 352
#define WW 352
#define RAD 5
#define TX 32
#define TY 32
#define LW (TX + 2*RAD)          // 42
#define LH (TY + 2*RAD)          // 42
#define LSTRIDE 43               // row stride in float4 units (odd -> spreads bank quads)
#define TILES_X (WW / TX)        // 11
#define TILES_Y (HH / TY)        // 11
#define NBLK (TILES_X * TILES_Y * NB)  // 968

// Pre-scale rgb by sqrt(ALPHA * log2(e)) so wgt = exp2(-sum(d^2))
#define RGB_SCALE 16.98644781888824f

typedef float f32x2 __attribute__((ext_vector_type(2)));

struct Half { float4 w[7]; };

// 7 ds_read_b128 with compile-time offsets off one base pointer.
__device__ __forceinline__ void load_half(Half& b, const float4* __restrict__ trow,
                                          int cidx /*compile-time*/) {
    #pragma unroll
    for (int j = 0; j < 7; ++j) b.w[j] = trow[cidx + j];
}

// One window float4 vs a PAIR of pre-negated packed centers.
// d = w + (-c) is bit-identical to w - c; sign of d irrelevant (squared).
__device__ __forceinline__ void tap_pair(const float4& w,
                                         f32x2 ncx, f32x2 ncy, f32x2 ncz, f32x2 ncw,
                                         float& aL, float& aH) {
    f32x2 d0 = ncx + w.x;        // pk_add with scalar broadcast
    f32x2 d1 = ncy + w.y;
    f32x2 d2 = ncz + w.z;
    f32x2 s  = d0 * d0;
    s += d1 * d1;                // pk_fma
    s += d2 * d2;
    f32x2 ds = ncw + w.w;
    aL = fmaf(__builtin_amdgcn_exp2f(-s.x), fabsf(ds.x), aL);
    aH = fmaf(__builtin_amdgcn_exp2f(-s.y), fabsf(ds.y), aH);
}

__device__ __forceinline__ void tap_scalar(const float4& w,
                                           float ncx, float ncy, float ncz, float ncw,
                                           float& a) {
    float d0 = w.x + ncx, d1 = w.y + ncy, d2 = w.z + ncz;
    float s = fmaf(d0, d0, fmaf(d1, d1, d2 * d2));
    a = fmaf(__builtin_amdgcn_exp2f(-s), fabsf(w.w + ncw), a);
}

// Separable 5x5 dil-ero mask for 4 x-adjacent pixels (reads .w of AoS tile).
template <bool INTERIOR>
__device__ __forceinline__ void compute_mask4(const float4* __restrict__ trow,
                                              int gy, int gx0, float* mask) {
    float cmx[8], cmn[8];
    #pragma unroll
    for (int j = 0; j < 8; ++j) {
        float mx = 0.f, mn = 1.f;
        #pragma unroll
        for (int r = 0; r < 5; ++r) {
            float l = (trow[(3 + r) * LSTRIDE + 3 + j].w > 0.5f) ? 1.f : 0.f;
            mx = fmaxf(mx, l);
            if (INTERIOR) {
                mn = fminf(mn, l);
            } else {
                bool rowv = (unsigned)(gy - 2 + r) < (unsigned)HH;
                mn = fminf(mn, rowv ? l : 1.f);
            }
        }
        cmx[j] = mx;
        if (INTERIOR) {
            cmn[j] = mn;
        } else {
            bool colv = (unsigned)(gx0 - 2 + j) < (unsigned)WW;
            cmn[j] = colv ? mn : 1.f;
        }
    }
    #pragma unroll
    for (int k = 0; k < 4; ++k) {
        float mx = cmx[k], mn = cmn[k];
        #pragma unroll
        for (int j2 = 1; j2 < 5; ++j2) {
            mx = fmaxf(mx, cmx[k + j2]);
            mn = fminf(mn, cmn[k + j2]);
        }
        mask[k] = mx - mn;  // 0 or 1
    }
}

__global__ __launch_bounds__(256, 4)
void btm_loss_kernel(const float* __restrict__ pred,
                     const float* __restrict__ feat,
                     float2* __restrict__ partials) {
    __shared__ float4 tile[LH * LSTRIDE];  // 42*43*16B = 28.9 KB
    __shared__ float2 wred[4];

    const int bid = blockIdx.x;
    const int tx_blk = bid % TILES_X;
    const int ty_blk = (bid / TILES_X) % TILES_Y;
    const int n = bid / (TILES_X * TILES_Y);
    const int x0 = tx_blk * TX;
    const int y0 = ty_blk * TY;

    const size_t plane = (size_t)HH * WW;
    const float* fr = feat + ((size_t)n * 3 + 0) * plane;
    const float* fg = feat + ((size_t)n * 3 + 1) * plane;
    const float* fb = feat + ((size_t)n * 3 + 2) * plane;
    const float* ps = pred + (size_t)n * plane;

    // ---- stage tile (zero-padded halo, matching jnp.pad; rgb pre-scaled) ----
    for (int i = threadIdx.x; i < LH * LW; i += 256) {
        int lr = i / LW;
        int lc = i - lr * LW;
        int gy = y0 + lr - RAD;
        int gx = x0 + lc - RAD;
        float4 v = make_float4(0.f, 0.f, 0.f, 0.f);
        if ((unsigned)gy < (unsigned)HH && (unsigned)gx < (unsigned)WW) {
            int gi = gy * WW + gx;
            v.x = fr[gi] * RGB_SCALE;
            v.y = fg[gi] * RGB_SCALE;
            v.z = fb[gi] * RGB_SCALE;
            v.w = ps[gi];
        }
        tile[lr * LSTRIDE + lc] = v;
    }
    __syncthreads();

    // Each thread owns 4 x-adjacent pixels; 256 threads cover the 32x32 tile.
    const int t   = threadIdx.x;
    const int txq = t & 7;       // 0..7
    const int ty  = t >> 3;      // 0..31
    const int px0 = txq * 4;

    // Base pointer: window row dy=0, col 0 for this thread. All main-loop LDS
    // accesses are compile-time offsets from here (fold to ds_read offset:N).
    const float4* trow = tile + ty * LSTRIDE + px0;

    // Centers (tile row ty+5, cols px0+5..+8), pre-negated packed pairs.
    float4 c0 = trow[RAD * LSTRIDE + RAD + 0];
    float4 c1 = trow[RAD * LSTRIDE + RAD + 1];
    float4 c2 = trow[RAD * LSTRIDE + RAD + 2];
    float4 c3 = trow[RAD * LSTRIDE + RAD + 3];
    f32x2 n01x = {-c0.x, -c1.x}, n01y = {-c0.y, -c1.y}, n01z = {-c0.z, -c1.z}, n01w = {-c0.w, -c1.w};
    f32x2 n23x = {-c2.x, -c3.x}, n23y = {-c2.y, -c3.y}, n23z = {-c2.z, -c3.z}, n23w = {-c2.w, -c3.w};

    float acc0 = 0.f, acc1 = 0.f, acc2 = 0.f, acc3 = 0.f;

    // Tap sets per half-row. Half h: window row h>>1, cols (h&1)*7 .. +6.
    //  lo (cols 0..6):  c0 scalar @0; c01 pairs @1..6; c2 scalar @2; c23 pairs @3..6
    //  hi (cols 7..13): c01 pairs @7..10; c1 scalar @11; c23 pairs @7..12; c3 scalar @13
    auto comp_lo = [&](const Half& b) {
        tap_scalar(b.w[0], n01x.x, n01y.x, n01z.x, n01w.x, acc0);
        #pragma unroll
        for (int j = 1; j <= 6; ++j) tap_pair(b.w[j], n01x, n01y, n01z, n01w, acc0, acc1);
        tap_scalar(b.w[2], n23x.x, n23y.x, n23z.x, n23w.x, acc2);
        #pragma unroll
        for (int j = 3; j <= 6; ++j) tap_pair(b.w[j], n23x, n23y, n23z, n23w, acc2, acc3);
    };
    auto comp_hi = [&](const Half& b) {
        #pragma unroll
        for (int j = 0; j <= 3; ++j) tap_pair(b.w[j], n01x, n01y, n01z, n01w, acc0, acc1);
        tap_scalar(b.w[4], n01x.y, n01y.y, n01z.y, n01w.y, acc1);
        #pragma unroll
        for (int j = 0; j <= 5; ++j) tap_pair(b.w[j], n23x, n23y, n23z, n23w, acc2, acc3);
        tap_scalar(b.w[6], n23x.y, n23y.y, n23z.y, n23w.y, acc3);
    };

    // Software pipeline: 22 half-rows, depth-2 register double-buffer.
    // Per step: issue next half's 7 ds_read_b128, FENCE, compute current half.
    // The fence stops the compiler from sinking loads into the taps (R1: it
    // did exactly that, VGPR_Count=60, per-tap lgkmcnt stalls).
    Half b0, b1;
    load_half(b0, trow, 0);

    #define STEP(H, BC, BP)                                                       \
        do {                                                                      \
            if ((H) + 1 < 22)                                                     \
                load_half(BP, trow, ((((H)+1) >> 1) * LSTRIDE + (((H)+1) & 1) * 7)); \
            __builtin_amdgcn_sched_barrier(0);                                    \
            if ((H) & 1) comp_hi(BC); else comp_lo(BC);                           \
        } while (0)

    STEP(0,  b0, b1);  STEP(1,  b1, b0);
    STEP(2,  b0, b1);  STEP(3,  b1, b0);
    STEP(4,  b0, b1);  STEP(5,  b1, b0);
    STEP(6,  b0, b1);  STEP(7,  b1, b0);
    STEP(8,  b0, b1);  STEP(9,  b1, b0);
    STEP(10, b0, b1);  STEP(11, b1, b0);
    STEP(12, b0, b1);  STEP(13, b1, b0);
    STEP(14, b0, b1);  STEP(15, b1, b0);
    STEP(16, b0, b1);  STEP(17, b1, b0);
    STEP(18, b0, b1);  STEP(19, b1, b0);
    STEP(20, b0, b1);  STEP(21, b1, b0);
    #undef STEP

    // ---- mask + per-thread num/den ----
    const int gy  = y0 + ty;
    const int gx0 = x0 + px0;
    float mask[4];
    const bool interior = (tx_blk >= 1) && (tx_blk <= TILES_X - 2) &&
                          (ty_blk >= 1) && (ty_blk <= TILES_Y - 2);
    if (interior) compute_mask4<true >(trow, gy, gx0, mask);
    else          compute_mask4<false>(trow, gy, gx0, mask);

    float num = fmaf(mask[0], acc0, fmaf(mask[1], acc1,
                fmaf(mask[2], acc2, mask[3] * acc3)));
    float den = (mask[0] + mask[1]) + (mask[2] + mask[3]);

    // ---- wave reduce -> block reduce -> deterministic partial store ----
    #pragma unroll
    for (int off = 32; off > 0; off >>= 1) {
        num += __shfl_down(num, off, 64);
        den += __shfl_down(den, off, 64);
    }
    const int wid  = t >> 6;
    const int lane = t & 63;
    if (lane == 0) wred[wid] = make_float2(num, den);
    __syncthreads();
    if (t == 0) {
        float2 a = wred[0];
        #pragma unroll
        for (int w = 1; w < 4; ++w) { a.x += wred[w].x; a.y += wred[w].y; }
        partials[bid] = a;
    }
}

__global__ __launch_bounds__(256)
void btm_finalize_kernel(const float2* __restrict__ partials,
                         float* __restrict__ out) {
    __shared__ float2 wred[4];
    float num = 0.f, den = 0.f;
    for (int i = threadIdx.x; i < NBLK; i += 256) {
        float2 p = partials[i];
        num += p.x;
        den += p.y;
    }
    #pragma unroll
    for (int off = 32; off > 0; off >>= 1) {
        num += __shfl_down(num, off, 64);
        den += __shfl_down(den, off, 64);
    }
    int wid  = threadIdx.x >> 6;
    int lane = threadIdx.x & 63;
    if (lane == 0) wred[wid] = make_float2(num, den);
    __syncthreads();
    if (threadIdx.x == 0) {
        float2 a = wred[0];
        #pragma unroll
        for (int w = 1; w < 4; ++w) { a.x += wred[w].x; a.y += wred[w].y; }
        out[0] = a.x / (a.y + 1e-6f);
    }
}

extern "C" void kernel_launch(void* const* d_in, const int* in_sizes, int n_in,
                              void* d_out, int out_size, void* d_ws, size_t ws_size,
                              hipStream_t stream) {
    const float* pred = (const float*)d_in[0];  // (8,1,352,352) fp32
    const float* feat = (const float*)d_in[1];  // (8,3,352,352) fp32
    float* out = (float*)d_out;                 // scalar fp32
    float2* partials = (float2*)d_ws;           // NBLK float2 = 7.7 KB

    btm_loss_kernel<<<dim3(NBLK), dim3(256), 0, stream>>>(pred, feat, partials);
    btm_finalize_kernel<<<dim3(1), dim3(256), 0, stream>>>(partials, out);
}

// Round 3
// 102.390 us; speedup vs baseline: 2.9585x; 2.9585x over previous
//
#include <hip/hip_runtime.h>

// Problem constants (match reference)
#define NB 8
#define HH 352
#define WW 352
#define RAD 5
#define TX 32
#define TY 32
#define LW (TX + 2*RAD)          // 42
#define LH (TY + 2*RAD)          // 42
#define LSTRIDE 43               // row stride in float4 units; odd -> (3*ty+j) mod 8 covers all bank quads
#define TILES_X (WW / TX)        // 11
#define TILES_Y (HH / TY)        // 11
#define NBLK (TILES_X * TILES_Y * NB)  // 968

// Pre-scale rgb by sqrt(ALPHA * log2(e)) so wgt = exp2(-sum(d^2))
#define RGB_SCALE 16.98644781888824f

typedef float f32x2 __attribute__((ext_vector_type(2)));

// One window float4 vs a PAIR of pre-negated packed centers.
// d = w + (-c) is bit-identical to w - c; sign irrelevant (squared / abs).
__device__ __forceinline__ void tap_pair(const float4& w,
                                         f32x2 ncx, f32x2 ncy, f32x2 ncz, f32x2 ncw,
                                         float& aL, float& aH) {
    f32x2 d0 = ncx + w.x;        // pk_add, scalar broadcast via op_sel
    f32x2 d1 = ncy + w.y;
    f32x2 d2 = ncz + w.z;
    f32x2 s  = d0 * d0;
    s += d1 * d1;                // pk_fma
    s += d2 * d2;
    f32x2 ds = ncw + w.w;
    aL = fmaf(__builtin_amdgcn_exp2f(-s.x), fabsf(ds.x), aL);
    aH = fmaf(__builtin_amdgcn_exp2f(-s.y), fabsf(ds.y), aH);
}

__device__ __forceinline__ void tap_scalar(const float4& w,
                                           float ncx, float ncy, float ncz, float ncw,
                                           float& a) {
    float d0 = w.x + ncx, d1 = w.y + ncy, d2 = w.z + ncz;
    float s = fmaf(d0, d0, fmaf(d1, d1, d2 * d2));
    a = fmaf(__builtin_amdgcn_exp2f(-s), fabsf(w.w + ncw), a);
}

// 5x5 dil-ero mask for 8 x-adjacent pixels (reads .w of AoS tile).
template <bool INTERIOR>
__device__ __forceinline__ void compute_mask8(const float4* __restrict__ trow,
                                              int gy, int gx0, float* mask) {
    float cmx[12], cmn[12];
    #pragma unroll
    for (int j = 0; j < 12; ++j) {
        float mx = 0.f, mn = 1.f;
        #pragma unroll
        for (int r = 0; r < 5; ++r) {
            float l = (trow[(3 + r) * LSTRIDE + 3 + j].w > 0.5f) ? 1.f : 0.f;
            mx = fmaxf(mx, l);
            if (INTERIOR) {
                mn = fminf(mn, l);
            } else {
                bool rowv = (unsigned)(gy - 2 + r) < (unsigned)HH;
                mn = fminf(mn, rowv ? l : 1.f);
            }
        }
        cmx[j] = mx;
        if (INTERIOR) {
            cmn[j] = mn;
        } else {
            bool colv = (unsigned)(gx0 - 2 + j) < (unsigned)WW;
            cmn[j] = colv ? mn : 1.f;
        }
    }
    #pragma unroll
    for (int k = 0; k < 8; ++k) {
        float mx = cmx[k], mn = cmn[k];
        #pragma unroll
        for (int j2 = 1; j2 < 5; ++j2) {
            mx = fmaxf(mx, cmx[k + j2]);
            mn = fminf(mn, cmn[k + j2]);
        }
        mask[k] = mx - mn;  // 0 or 1
    }
}

__global__ __launch_bounds__(256, 2)
void btm_loss_kernel(const float* __restrict__ pred,
                     const float* __restrict__ feat,
                     float2* __restrict__ partials) {
    __shared__ float4 tile[LH * LSTRIDE];  // 42*43*16B = 28.9 KB
    __shared__ float4 xchA[128], xchB[128];  // dy-split partial-acc exchange (4 KB)
    __shared__ float2 wred[4];

    const int bid = blockIdx.x;
    const int tx_blk = bid % TILES_X;
    const int ty_blk = (bid / TILES_X) % TILES_Y;
    const int n = bid / (TILES_X * TILES_Y);
    const int x0 = tx_blk * TX;
    const int y0 = ty_blk * TY;

    const size_t plane = (size_t)HH * WW;
    const float* fr = feat + ((size_t)n * 3 + 0) * plane;
    const float* fg = feat + ((size_t)n * 3 + 1) * plane;
    const float* fb = feat + ((size_t)n * 3 + 2) * plane;
    const float* ps = pred + (size_t)n * plane;

    // ---- stage tile (zero-padded halo, matching jnp.pad; rgb pre-scaled) ----
    for (int i = threadIdx.x; i < LH * LW; i += 256) {
        int lr = i / LW;
        int lc = i - lr * LW;
        int gy = y0 + lr - RAD;
        int gx = x0 + lc - RAD;
        float4 v = make_float4(0.f, 0.f, 0.f, 0.f);
        if ((unsigned)gy < (unsigned)HH && (unsigned)gx < (unsigned)WW) {
            int gi = gy * WW + gx;
            v.x = fr[gi] * RGB_SCALE;
            v.y = fg[gi] * RGB_SCALE;
            v.z = fb[gi] * RGB_SCALE;
            v.w = ps[gi];
        }
        tile[lr * LSTRIDE + lc] = v;
    }
    __syncthreads();

    // 2 dy-groups x (4 x-groups x 32 rows). Each thread owns 8 x-adjacent px.
    const int t   = threadIdx.x;
    const int g   = t >> 7;      // 0: dy 0..5, 1: dy 6..10 (wave-uniform)
    const int tl  = t & 127;
    const int txg = tl & 3;      // 0..3
    const int ty  = tl >> 2;     // 0..31
    const int px0 = txg * 8;

    // Base pointer: window row dy=0, col 0 for this thread's strip.
    const float4* trow = tile + ty * LSTRIDE + px0;

    // Centers (tile row ty+5, cols px0+5..+12), pre-negated packed pairs.
    f32x2 npx[4], npy[4], npz[4], npw[4];
    #pragma unroll
    for (int p = 0; p < 4; ++p) {
        float4 ca = trow[RAD * LSTRIDE + RAD + 2 * p];
        float4 cb = trow[RAD * LSTRIDE + RAD + 2 * p + 1];
        npx[p].x = -ca.x; npx[p].y = -cb.x;
        npy[p].x = -ca.y; npy[p].y = -cb.y;
        npz[p].x = -ca.z; npz[p].y = -cb.z;
        npw[p].x = -ca.w; npw[p].y = -cb.w;
    }

    float acc0 = 0.f, acc1 = 0.f, acc2 = 0.f, acc3 = 0.f;
    float acc4 = 0.f, acc5 = 0.f, acc6 = 0.f, acc7 = 0.f;

    const int dy_lo = g ? 6 : 0;
    const int dy_hi = g ? 11 : 6;
    for (int dy = dy_lo; dy < dy_hi; ++dy) {
        const float4* row = trow + dy * LSTRIDE;
        float4 w[18];
        #pragma unroll
        for (int j = 0; j < 18; ++j) w[j] = row[j];

        // Center pair p covers pixels (2p, 2p+1):
        //   scalar c_{2p} @ w[2p]; pairs @ w[2p+1 .. 2p+10]; scalar c_{2p+1} @ w[2p+11]
        #define PAIRSET(P, AL, AH)                                              \
            do {                                                                \
                tap_scalar(w[2*(P)],     npx[P].x, npy[P].x, npz[P].x, npw[P].x, AL); \
                _Pragma("unroll")                                               \
                for (int j = 2*(P) + 1; j <= 2*(P) + 10; ++j)                   \
                    tap_pair(w[j], npx[P], npy[P], npz[P], npw[P], AL, AH);     \
                tap_scalar(w[2*(P) + 11], npx[P].y, npy[P].y, npz[P].y, npw[P].y, AH); \
            } while (0)

        PAIRSET(0, acc0, acc1);
        PAIRSET(1, acc2, acc3);
        PAIRSET(2, acc4, acc5);
        PAIRSET(3, acc6, acc7);
        #undef PAIRSET
    }

    // ---- exchange: group 1 hands its partial accs to group 0 ----
    if (g == 1) {
        xchA[tl] = make_float4(acc0, acc1, acc2, acc3);
        xchB[tl] = make_float4(acc4, acc5, acc6, acc7);
    }
    __syncthreads();

    float num = 0.f, den = 0.f;
    if (g == 0) {
        float4 oA = xchA[tl], oB = xchB[tl];
        acc0 += oA.x; acc1 += oA.y; acc2 += oA.z; acc3 += oA.w;
        acc4 += oB.x; acc5 += oB.y; acc6 += oB.z; acc7 += oB.w;

        const int gy  = y0 + ty;
        const int gx0 = x0 + px0;
        float mask[8];
        const bool interior = (tx_blk >= 1) && (tx_blk <= TILES_X - 2) &&
                              (ty_blk >= 1) && (ty_blk <= TILES_Y - 2);
        if (interior) compute_mask8<true >(trow, gy, gx0, mask);
        else          compute_mask8<false>(trow, gy, gx0, mask);

        num = fmaf(mask[0], acc0, fmaf(mask[1], acc1,
              fmaf(mask[2], acc2, fmaf(mask[3], acc3,
              fmaf(mask[4], acc4, fmaf(mask[5], acc5,
              fmaf(mask[6], acc6, mask[7] * acc7)))))));
        den = ((mask[0] + mask[1]) + (mask[2] + mask[3])) +
              ((mask[4] + mask[5]) + (mask[6] + mask[7]));
    }

    // ---- wave reduce -> block reduce -> deterministic partial store ----
    #pragma unroll
    for (int off = 32; off > 0; off >>= 1) {
        num += __shfl_down(num, off, 64);
        den += __shfl_down(den, off, 64);
    }
    const int wid  = t >> 6;
    const int lane = t & 63;
    if (lane == 0) wred[wid] = make_float2(num, den);
    __syncthreads();
    if (t == 0) {
        float2 a = wred[0];
        #pragma unroll
        for (int w2 = 1; w2 < 4; ++w2) { a.x += wred[w2].x; a.y += wred[w2].y; }
        partials[bid] = a;
    }
}

__global__ __launch_bounds__(256)
void btm_finalize_kernel(const float2* __restrict__ partials,
                         float* __restrict__ out) {
    __shared__ float2 wred[4];
    float num = 0.f, den = 0.f;
    for (int i = threadIdx.x; i < NBLK; i += 256) {
        float2 p = partials[i];
        num += p.x;
        den += p.y;
    }
    #pragma unroll
    for (int off = 32; off > 0; off >>= 1) {
        num += __shfl_down(num, off, 64);
        den += __shfl_down(den, off, 64);
    }
    int wid  = threadIdx.x >> 6;
    int lane = threadIdx.x & 63;
    if (lane == 0) wred[wid] = make_float2(num, den);
    __syncthreads();
    if (threadIdx.x == 0) {
        float2 a = wred[0];
        #pragma unroll
        for (int w = 1; w < 4; ++w) { a.x += wred[w].x; a.y += wred[w].y; }
        out[0] = a.x / (a.y + 1e-6f);
    }
}

extern "C" void kernel_launch(void* const* d_in, const int* in_sizes, int n_in,
                              void* d_out, int out_size, void* d_ws, size_t ws_size,
                              hipStream_t stream) {
    const float* pred = (const float*)d_in[0];  // (8,1,352,352) fp32
    const float* feat = (const float*)d_in[1];  // (8,3,352,352) fp32
    float* out = (float*)d_out;                 // scalar fp32
    float2* partials = (float2*)d_ws;           // NBLK float2 = 7.7 KB

    btm_loss_kernel<<<dim3(NBLK), dim3(256), 0, stream>>>(pred, feat, partials);
    btm_finalize_kernel<<<dim3(1), dim3(256), 0, stream>>>(partials, out);
}